// Round 10
// baseline (108.866 us; speedup 1.0000x reference)
//
#include <hip/hip_runtime.h>
#include <stdint.h>

#define NQ 10
#define DIMQ 1024
#define BATCH 4096

typedef float f32x2 __attribute__((ext_vector_type(2)));

#if __has_builtin(__builtin_amdgcn_permlane16_swap)
#define HAS_PL16 1
#else
#define HAS_PL16 0
#endif

// ------------------------------------------------------- gate coefficients ---
// Per gate: 8 pre-packed f32x2 so every butterfly term is coef*v +
// coef2*swap(v) (pure v_pk_fma_f32, negations baked into the data).
__global__ __launch_bounds__(64) void prep_g(const float* __restrict__ wts,
                                             float* __restrict__ Gg) {
  int g = threadIdx.x;
  if (g < 40) {
    float phi = wts[g * 3 + 0], th = wts[g * 3 + 1], om = wts[g * 3 + 2];
    float ct = cosf(0.5f * th), s = sinf(0.5f * th);
    float ap = 0.5f * (phi + om), am = 0.5f * (phi - om);
    float cp = cosf(ap), spp = sinf(ap), cm = cosf(am), sm = sinf(am);
    float aR = ct * cp,  aI = -ct * spp;
    float bR = -s * cm,  bI = -s * sm;
    float cR = s * cm,   cI = -s * sm;
    float dR = ct * cp,  dI = ct * spp;
    float* o = Gg + g * 16;
    o[0]  = aR;  o[1]  = aR;  o[2]  = -aI; o[3]  = aI;
    o[4]  = bR;  o[5]  = bR;  o[6]  = -bI; o[7]  = bI;
    o[8]  = cR;  o[9]  = cR;  o[10] = -cI; o[11] = cI;
    o[12] = dR;  o[13] = dR;  o[14] = -dI; o[15] = dI;
  }
}

// Layer's 10 CNOTs composed as a GF(2)-linear index map (scatter form).
__host__ __device__ constexpr int cperm_c(int x, int r) {
  for (int q = 0; q < NQ; ++q) {
    const int c = 9 - q;
    int t = c - r; if (t < 0) t += NQ;
    x ^= ((x >> c) & 1) << t;
  }
  return x;
}
// Epilogue sign masks (layer-3 perm r=4 folded into signs).
constexpr int amask(int q) {
  int a = 0;
  for (int b = 0; b < 6; ++b) a |= ((cperm_c(1 << b, 4) >> (9 - q)) & 1) << b;
  return a;
}
constexpr int mmask(int q) {
  int m = 0;
  for (int b = 0; b < 4; ++b) m |= ((cperm_c(1 << (6 + b), 4) >> (9 - q)) & 1) << b;
  return m;
}

__device__ __forceinline__ f32x2 swapv(f32x2 v) {
  return __builtin_shufflevector(v, v, 1, 0);
}

// ---- VALU-pipe lane shuffles ----
template<int CTRL>
__device__ __forceinline__ float dpp1(float x) {
  return __int_as_float(
      __builtin_amdgcn_update_dpp(0, __float_as_int(x), CTRL, 0xF, 0xF, true));
}
// quad_perm xor1=0xB1, xor2=0x4E, xor3=0x1B; row_mirror(^15)=0x140,
// row_half_mirror(^7)=0x141. ^4 = ^7 o ^3, ^8 = ^15 o ^7.
template<int P>   // P = lane bit, 0..3 (DPP only)
__device__ __forceinline__ float shufl(float x) {
  if constexpr (P == 0)      return dpp1<0xB1>(x);
  else if constexpr (P == 1) return dpp1<0x4E>(x);
  else if constexpr (P == 2) return dpp1<0x141>(dpp1<0x1B>(x));
  else                       return dpp1<0x140>(dpp1<0x141>(x));
}

// xor16 partner: permlane16_swap (VALU) if available, else ds_swizzle (DS).
__device__ __forceinline__ float x16(float x, bool hi) {
#if HAS_PL16
  auto rr = __builtin_amdgcn_permlane16_swap(__float_as_uint(x),
                                             __float_as_uint(x), false, false);
  return __uint_as_float(hi ? rr[0] : rr[1]);   // rr[0]=x[lane&~16], rr[1]=x[lane|16]
#else
  (void)hi;
  return __int_as_float(__builtin_amdgcn_ds_swizzle(__float_as_int(x), 0x401F));
#endif
}

// Wave sum -> uniform scalar (all-VALU when permlane16 exists).
__device__ __forceinline__ float red64(float v) {
  v += dpp1<0xB1>(v);
  v += dpp1<0x4E>(v);
  v += dpp1<0x141>(dpp1<0x1B>(v));   // ^4
  v += dpp1<0x140>(dpp1<0x141>(v));  // ^8
#if HAS_PL16
  { auto rr = __builtin_amdgcn_permlane16_swap(__float_as_uint(v),
                                               __float_as_uint(v), false, false);
    v = __uint_as_float(rr[0]) + __uint_as_float(rr[1]); }
#else
  v += __int_as_float(__builtin_amdgcn_ds_swizzle(__float_as_int(v), 0x401F));
#endif
  auto p = __builtin_amdgcn_permlane32_swap(__float_as_uint(v),
                                            __float_as_uint(v), false, false);
  return __uint_as_float(p[0]) + __uint_as_float(p[1]);
}

// ---- gates over TWO rows (s[0..15] = row A, s[16..31] = row B) ----
template<int MT>
__device__ __forceinline__ void rotR2(f32x2 (&s)[32], const f32x2* __restrict__ C) {
  const f32x2 C0 = C[0], C1 = C[1], C2 = C[2], C3 = C[3];
  const f32x2 C4 = C[4], C5 = C[5], C6 = C[6], C7 = C[7];
  #pragma unroll
  for (int g = 0; g < 32; g += 16)
    #pragma unroll
    for (int e0 = 0; e0 < 16; ++e0) {
      if (e0 & MT) continue;
      const int i0 = g + e0, i1 = g + (e0 | MT);
      f32x2 x0 = s[i0], x1 = s[i1], w0 = swapv(x0), w1 = swapv(x1);
      s[i0] = C0 * x0 + C1 * w0 + C2 * x1 + C3 * w1;
      s[i1] = C4 * x0 + C5 * w0 + C6 * x1 + C7 * w1;
    }
}

template<int P>   // lane bits 0..3 via DPP
__device__ __forceinline__ void rotL2(f32x2 (&s)[32], const f32x2* __restrict__ C,
                                      int lane) {
  const int L = (lane >> P) & 1;
  const f32x2 A0 = L ? C[6] : C[0], A1 = L ? C[7] : C[1];
  const f32x2 B0 = L ? C[4] : C[2], B1 = L ? C[5] : C[3];
  #pragma unroll
  for (int i = 0; i < 32; ++i) {
    f32x2 o;
    o.x = shufl<P>(s[i].x);
    o.y = shufl<P>(s[i].y);
    s[i] = A0 * s[i] + A1 * swapv(s[i]) + B0 * o + B1 * swapv(o);
  }
}

// lane bit 4 (xor16)
__device__ __forceinline__ void rot16_2(f32x2 (&s)[32], const f32x2* __restrict__ C,
                                        int lane) {
  const bool H = (lane & 16) != 0;
  const f32x2 A0 = H ? C[6] : C[0], A1 = H ? C[7] : C[1];
  const f32x2 B0 = H ? C[4] : C[2], B1 = H ? C[5] : C[3];
  #pragma unroll
  for (int i = 0; i < 32; ++i) {
    f32x2 o;
    o.x = x16(s[i].x, H);
    o.y = x16(s[i].y, H);
    s[i] = A0 * s[i] + A1 * swapv(s[i]) + B0 * o + B1 * swapv(o);
  }
}

// lane bit 5 (xor32): permlane32_swap (R7-verified pattern)
__device__ __forceinline__ void rot5_2(f32x2 (&s)[32], const f32x2* __restrict__ C,
                                       int lane) {
  const int L = lane >> 5;
  const f32x2 A0 = L ? C[6] : C[0], A1 = L ? C[7] : C[1];
  const f32x2 B0 = L ? C[4] : C[2], B1 = L ? C[5] : C[3];
  #pragma unroll
  for (int i = 0; i < 32; ++i) {
    unsigned xr = __float_as_uint(s[i].x), xi = __float_as_uint(s[i].y);
    auto rr = __builtin_amdgcn_permlane32_swap(xr, xr, false, false);
    auto ri = __builtin_amdgcn_permlane32_swap(xi, xi, false, false);
    f32x2 o;
    o.x = __uint_as_float(L ? rr[0] : rr[1]);
    o.y = __uint_as_float(L ? ri[0] : ri[1]);
    s[i] = A0 * s[i] + A1 * swapv(s[i]) + B0 * o + B1 * swapv(o);
  }
}

// CNOT permutation: each row through its own private LDS slice (same-wave DS
// in-order, no barrier). Templated masks stay compile-time.
template<int R>
__device__ __forceinline__ void perm2(f32x2 (&s)[32], f32x2* __restrict__ L0,
                                      f32x2* __restrict__ L1, int lane) {
  constexpr int K0=cperm_c(1,R),  K1=cperm_c(2,R),  K2=cperm_c(4,R),
                K3=cperm_c(8,R),  K4=cperm_c(16,R), K5=cperm_c(32,R),
                C6=cperm_c(64,R), C7=cperm_c(128,R),
                C8=cperm_c(256,R),C9=cperm_c(512,R);
  const int yl = ((lane & 1)  ? K0 : 0) ^ ((lane & 2)  ? K1 : 0) ^
                 ((lane & 4)  ? K2 : 0) ^ ((lane & 8)  ? K3 : 0) ^
                 ((lane & 16) ? K4 : 0) ^ ((lane & 32) ? K5 : 0);
  #pragma unroll
  for (int e = 0; e < 16; ++e) {
    const int y = yl ^ (((e & 1) ? C6 : 0) ^ ((e & 2) ? C7 : 0) ^
                        ((e & 4) ? C8 : 0) ^ ((e & 8) ? C9 : 0));
    L0[y] = s[e];
    L1[y] = s[16 + e];
  }
  #pragma unroll
  for (int e = 0; e < 16; ++e) {
    s[e]      = L0[(e << 6) | lane];
    s[16 + e] = L1[(e << 6) | lane];
  }
}

// In-register Walsh-Hadamard stage over the 4 e-bits.
template<int M>
__device__ __forceinline__ void wht(float (&h)[16]) {
  #pragma unroll
  for (int e0 = 0; e0 < 16; ++e0) {
    if (e0 & M) continue;
    float u = h[e0], v = h[e0 | M];
    h[e0] = u + v;
    h[e0 | M] = u - v;
  }
}

template<int Q>
__device__ __forceinline__ float zfin(const float (&h)[16], int lane, float rn2) {
  constexpr int aq = amask(Q);
  constexpr int mq = mmask(Q);
  float t = h[mq];
  if constexpr (aq != 0) {
    int par = __builtin_popcount(lane & aq) & 1;
    t = par ? -t : t;
  }
  return red64(t) * rn2;
}

// ------------------------------------------------------- fused simulation ---
// TWO rows per wave (R9 post-mortem: 63% per-SIMD issue, 37% stall; grid caps
// TLP so add ILP instead — 32 independent butterflies/gate). Layer loop
// ROLLED so the ~25 KB body gets I$ reuse (unrolled 2-row would be ~90 KB of
// straight-line streaming code). Zero __syncthreads; per-row private LDS.
__global__ __launch_bounds__(256, 2) void vqc_sim(const float* __restrict__ X,
                                                  const float* __restrict__ Gg,
                                                  const float* __restrict__ W,
                                                  const float* __restrict__ bias,
                                                  float* __restrict__ out) {
  __shared__ f32x2 lds[4][2][DIMQ];   // 64 KB: 2 slices per wave
  const int lane = threadIdx.x & 63;
  const int w = threadIdx.x >> 6;
  const int row0 = (blockIdx.x * 4 + w) * 2;
  f32x2* L0 = lds[w][0];
  f32x2* L1 = lds[w][1];
  const f32x2* Cq = (const f32x2*)Gg;

  f32x2 s[32];
  float rn2[2];

  // ---- load both rows (coalesced; norm deferred to epilogue) ----
  const float* xr = X + (size_t)row0 * DIMQ;
  #pragma unroll
  for (int r = 0; r < 2; ++r) {
    float ss = 0.f;
    #pragma unroll
    for (int e = 0; e < 16; ++e) {
      float v = xr[r * DIMQ + (e << 6) + lane];
      s[r * 16 + e].x = v;
      s[r * 16 + e].y = 0.f;
      ss += v * v;
    }
    rn2[r] = 1.0f / red64(ss);
  }

  // ---- 4 layers, loop rolled (I$ reuse); all state indices static ----
  #pragma unroll 1
  for (int l = 0; l < 4; ++l) {
    const f32x2* G = Cq + l * 80;
    rotR2<8>(s, G);              // q0 -> bit9
    rotR2<4>(s, G + 8);          // q1 -> bit8
    rotR2<2>(s, G + 16);         // q2 -> bit7
    rotR2<1>(s, G + 24);         // q3 -> bit6
    rot5_2 (s, G + 32, lane);    // q4 -> bit5 (permlane32_swap)
    rot16_2(s, G + 40, lane);    // q5 -> bit4 (permlane16_swap / swizzle)
    rotL2<3>(s, G + 48, lane);   // q6 -> bit3 (DPP)
    rotL2<2>(s, G + 56, lane);   // q7 -> bit2 (DPP)
    rotL2<1>(s, G + 64, lane);   // q8 -> bit1 (DPP)
    rotL2<0>(s, G + 72, lane);   // q9 -> bit0 (DPP)
    if (l == 0)      perm2<1>(s, L0, L1, lane);
    else if (l == 1) perm2<2>(s, L0, L1, lane);
    else if (l == 2) perm2<3>(s, L0, L1, lane);
    // layer 3's permutation (r=4) folded into the epilogue sign masks
  }

  // ---- per row: probs -> WHT -> z -> linear head ----
  #pragma unroll
  for (int r = 0; r < 2; ++r) {
    float h[16];
    #pragma unroll
    for (int e = 0; e < 16; ++e) {
      f32x2 t = s[r * 16 + e];
      h[e] = t.x * t.x + t.y * t.y;
    }
    wht<1>(h); wht<2>(h); wht<4>(h); wht<8>(h);

    float z[10];
    z[0] = zfin<0>(h, lane, rn2[r]);
    z[1] = zfin<1>(h, lane, rn2[r]);
    z[2] = zfin<2>(h, lane, rn2[r]);
    z[3] = zfin<3>(h, lane, rn2[r]);
    z[4] = zfin<4>(h, lane, rn2[r]);
    z[5] = zfin<5>(h, lane, rn2[r]);
    z[6] = zfin<6>(h, lane, rn2[r]);
    z[7] = zfin<7>(h, lane, rn2[r]);
    z[8] = zfin<8>(h, lane, rn2[r]);
    z[9] = zfin<9>(h, lane, rn2[r]);

    if (lane < 16) {
      float acc = bias[lane];
      #pragma unroll
      for (int q = 0; q < 10; ++q) acc += z[q] * W[lane * 10 + q];
      out[(size_t)(row0 + r) * 16 + lane] = acc;
    }
  }
}

extern "C" void kernel_launch(void* const* d_in, const int* in_sizes, int n_in,
                              void* d_out, int out_size, void* d_ws, size_t ws_size,
                              hipStream_t stream) {
  const float* X    = (const float*)d_in[0];
  const float* wts  = (const float*)d_in[1];
  const float* W    = (const float*)d_in[2];
  const float* bias = (const float*)d_in[3];
  float* out = (float*)d_out;
  float* Gg = (float*)d_ws;   // 40 gates x 16 floats = 2.5 KB

  hipLaunchKernelGGL(prep_g,  dim3(1),         dim3(64),  0, stream, wts, Gg);
  hipLaunchKernelGGL(vqc_sim, dim3(BATCH / 8), dim3(256), 0, stream, X, Gg, W, bias, out);
}